// Round 2
// baseline (229.808 us; speedup 1.0000x reference)
//
#include <hip/hip_runtime.h>

#define N_RAYS 65536
#define N_PTS  128
#define FEAT   3
#define FAR_DELTA 1e10f

#define BLOCK  256
#define NCHUNK 32          // 4 samples per chunk, 32 chunks = 128 samples
#define SLOTS  5           // f4 slots per chunk per lane: depth, density, feat x3

// Thread-per-ray sequential volume rendering with a 3-deep global->LDS DMA
// pipeline. Each wave DMAs its own 64 rays' chunk data (global_load_lds,
// wave-uniform LDS base + lane*16) into a wave-private triple buffer and
// paces itself with counted s_waitcnt vmcnt(10) -- two chunks always in
// flight, never drained to 0. No __syncthreads (would force vmcnt(0)),
// no shuffles (no ds_bpermute latency chains), no cross-wave sharing.
__global__ __launch_bounds__(BLOCK) void volrend_kernel(
    const float* __restrict__ depth,
    const float* __restrict__ density,
    const float* __restrict__ feature,
    float* __restrict__ out)
{
    // [wave][buffer][slot][lane] -- 4 * 3 * 5 * 64 * 16 B = 60 KB
    __shared__ float4 sbuf[4][3][SLOTS][64];

    const int tid = threadIdx.x;
    const int w   = tid >> 6;
    const int L   = tid & 63;
    const int ray = (int)blockIdx.x * BLOCK + tid;   // one ray per thread

    const float* dp = depth   + (size_t)ray * N_PTS;
    const float* rp = density + (size_t)ray * N_PTS;
    const float* fp = feature + (size_t)ray * (N_PTS * FEAT);

    float4 (*buf)[SLOTS][64] = sbuf[w];   // wave-private [3][5][64]

    // One chunk = 5 DMA loads of 64 lanes x 16 B (lane L's data lands at
    // slot base + L*16, exactly where thread (w*64+L) will read it back).
#define GLD(gp_, lp_)                                                         \
    __builtin_amdgcn_global_load_lds(                                         \
        (const __attribute__((address_space(1))) void*)(gp_),                 \
        (__attribute__((address_space(3))) void*)(lp_), 16, 0, 0)

#define ISSUE(c_, b_)                                                         \
    do {                                                                      \
        GLD(dp + (c_) * 4,      &buf[b_][0][0]);                              \
        GLD(rp + (c_) * 4,      &buf[b_][1][0]);                              \
        GLD(fp + (c_) * 12,     &buf[b_][2][0]);                              \
        GLD(fp + (c_) * 12 + 4, &buf[b_][3][0]);                              \
        GLD(fp + (c_) * 12 + 8, &buf[b_][4][0]);                              \
    } while (0)

    ISSUE(0, 0);
    ISSUE(1, 1);

    float cum = 0.0f, T = 1.0f;               // running -log T and T
    float a0 = 0.f, a1 = 0.f, a2 = 0.f, a3 = 0.f;
    float pd = 0.f, pr = 0.f, pf0 = 0.f, pf1 = 0.f, pf2 = 0.f;  // carried sample

    // w_i = exp(-cum_{i-1}) - exp(-cum_i): dependency chain is adds only;
    // exps are off-chain and overlap.
#define STEP(dv_, rv_, del_, fr_, fg_, fb_)                                   \
    do {                                                                      \
        float tau_ = (rv_) * (del_);                                          \
        cum += tau_;                                                          \
        float Tn_ = __expf(-cum);                                             \
        float w_  = T - Tn_;                                                  \
        a0 += w_ * (fr_); a1 += w_ * (fg_);                                   \
        a2 += w_ * (fb_); a3 += w_ * (dv_);                                   \
        T = Tn_;                                                              \
    } while (0)

#pragma unroll
    for (int c = 0; c < NCHUNK; ++c) {
        if (c + 2 < NCHUNK) ISSUE(c + 2, (c + 2) % 3);

        // Wait only for chunk c's 5 loads (the 10 newer ones stay in flight).
        if (c < NCHUNK - 2)       asm volatile("s_waitcnt vmcnt(10)" ::: "memory");
        else if (c == NCHUNK - 2) asm volatile("s_waitcnt vmcnt(5)"  ::: "memory");
        else                      asm volatile("s_waitcnt vmcnt(0)"  ::: "memory");

        const int b = c % 3;
        float4 dv = buf[b][0][L];   // depth  samples 4c..4c+3
        float4 rv = buf[b][1][L];   // density
        float4 f0 = buf[b][2][L];   // feature floats 12c..12c+3
        float4 f1 = buf[b][3][L];   // floats +4..+7
        float4 f2 = buf[b][4][L];   // floats +8..+11

        // carried sample 4c-1: its delta needs this chunk's first depth
        if (c > 0) STEP(pd, pr, dv.x - pd, pf0, pf1, pf2);

        STEP(dv.x, rv.x, dv.y - dv.x, f0.x, f0.y, f0.z);
        STEP(dv.y, rv.y, dv.z - dv.y, f0.w, f1.x, f1.y);
        STEP(dv.z, rv.z, dv.w - dv.z, f1.z, f1.w, f2.x);

        pd  = dv.w;  pr  = rv.w;               // carry sample 4c+3
        pf0 = f2.y;  pf1 = f2.z;  pf2 = f2.w;
    }

    // last sample (127) with the sentinel delta: tau ~ 1e10 -> T_next = 0
    STEP(pd, pr, FAR_DELTA, pf0, pf1, pf2);

    *(float4*)(out + (size_t)ray * 4) = make_float4(a0, a1, a2, a3);

#undef STEP
#undef ISSUE
#undef GLD
}

extern "C" void kernel_launch(void* const* d_in, const int* in_sizes, int n_in,
                              void* d_out, int out_size, void* d_ws, size_t ws_size,
                              hipStream_t stream) {
    const float* depth   = (const float*)d_in[0];
    const float* density = (const float*)d_in[1];
    const float* feature = (const float*)d_in[2];
    float* out = (float*)d_out;

    dim3 grid(N_RAYS / BLOCK);   // 256 blocks: one per CU, 4 waves each
    dim3 block(BLOCK);
    volrend_kernel<<<grid, block, 0, stream>>>(depth, density, feature, out);
}

// Round 3
// 194.609 us; speedup vs baseline: 1.1809x; 1.1809x over previous
//
#include <hip/hip_runtime.h>

#define N_RAYS 65536
#define N_PTS  128
#define FAR_DELTA 1e10f

#define BLOCK   256
#define NBLOCKS 2048                         // 8 blocks/CU nominal
#define NWAVES  (NBLOCKS * (BLOCK / 64))     // 8192 waves
#define NPAIRS  (N_RAYS / 2)                 // 32768 ray-pairs
#define NPASS   (NPAIRS / NWAVES)            // 4 pairs per wave

// 2 rays per wave (32-lane segments, 4 samples/lane). All global loads are
// wave-contiguous float4 (depth/density: 1 each; feature: 3, covering both
// rays' 1536-B rows exactly once). Register-held depth-1 prefetch keeps the
// next pair's 5 KB in flight under the current pair's compute -- no LDS, no
// barriers, no block churn. Pass-strided ray assignment sweeps contiguous
// 40-MB slabs for L2/L3 locality.
__global__ __launch_bounds__(BLOCK, 6) void volrend_kernel(
    const float* __restrict__ depth,
    const float* __restrict__ density,
    const float* __restrict__ feature,
    float* __restrict__ out)
{
    const int lane = threadIdx.x & 63;
    const int sl   = lane & 31;               // lane within 32-lane segment
    const int g    = (int)blockIdx.x * (BLOCK / 64) + (threadIdx.x >> 6);

    float4 d, rho, f0, f1, f2;                // current ray-pair
    float4 pd, pr, pf0, pf1, pf2;             // prefetched next pair

    // pair p owns rays 2p (lanes 0-31) and 2p+1 (lanes 32-63).
    // depth/density: float index 2p*128 + 4*lane  (wave-contiguous 1 KB)
    // feature:       float index 2p*384 + 12*lane (wave-contiguous 3 KB)
#define LOADP(p_, D_, R_, F0_, F1_, F2_)                                      \
    do {                                                                      \
        size_t rb_ = (size_t)(2 * (p_)) * N_PTS + 4 * lane;                   \
        D_ = *(const float4*)(depth + rb_);                                   \
        R_ = *(const float4*)(density + rb_);                                 \
        const float* fp_ = feature + (size_t)(2 * (p_)) * (N_PTS * 3)         \
                         + 12 * lane;                                         \
        F0_ = *(const float4*)(fp_);                                          \
        F1_ = *(const float4*)(fp_ + 4);                                      \
        F2_ = *(const float4*)(fp_ + 8);                                      \
    } while (0)

    LOADP(g, d, rho, f0, f1, f2);

#pragma unroll
    for (int p = 0; p < NPASS; ++p) {
        // issue next pair's loads before touching this pair's data
        if (p + 1 < NPASS)
            LOADP((p + 1) * NWAVES + g, pd, pr, pf0, pf1, pf2);

        // ---- per-lane taus (4 samples) + in-register local prefix ----
        float nx = __shfl_down(d.x, 1);       // next lane's first depth
        float t0 = rho.x * (d.y - d.x);
        float t1 = rho.y * (d.z - d.y);
        float t2 = rho.z * (d.w - d.z);
        float t3 = rho.w * ((sl == 31) ? FAR_DELTA : (nx - d.w));
        float q1 = t0, q2 = q1 + t1, q3 = q2 + t2, tot = q3 + t3;

        // ---- segmented exclusive scan (shift-then-inclusive; sentinel tau
        //      of sl==31 never enters any lane's exclusive sum) ----
        float e = __shfl_up(tot, 1);
        if (sl == 0) e = 0.0f;
        #pragma unroll
        for (int off = 1; off < 32; off <<= 1) {
            float u = __shfl_up(e, off);
            if (sl >= off) e += u;            // sl-guard masks cross-segment pulls
        }

        float T0 = __expf(-e);
        float T1 = __expf(-(e + q1));
        float T2 = __expf(-(e + q2));
        float T3 = __expf(-(e + q3));
        float T4 = __expf(-(e + tot));        // sl==31: exp(-1e10*rho) -> 0
        float w0 = T0 - T1, w1 = T1 - T2, w2 = T2 - T3, w3 = T3 - T4;

        float a3 = w0 * d.x  + w1 * d.y  + w2 * d.z  + w3 * d.w;
        float a0 = w0 * f0.x + w1 * f0.w + w2 * f1.z + w3 * f2.y;
        float a1 = w0 * f0.y + w1 * f1.x + w2 * f1.w + w3 * f2.z;
        float a2 = w0 * f0.z + w1 * f1.y + w2 * f2.x + w3 * f2.w;

        // ---- segmented reduction (xor butterfly stays inside 32 lanes) ----
        #pragma unroll
        for (int off = 16; off > 0; off >>= 1) {
            a0 += __shfl_xor(a0, off);
            a1 += __shfl_xor(a1, off);
            a2 += __shfl_xor(a2, off);
            a3 += __shfl_xor(a3, off);
        }
        if (sl == 0) {
            int ray = 2 * (p * NWAVES + g) + (lane >> 5);
            *(float4*)(out + (size_t)ray * 4) = make_float4(a0, a1, a2, a3);
        }

        d = pd; rho = pr; f0 = pf0; f1 = pf1; f2 = pf2;   // rotate pipeline
    }
#undef LOADP
}

extern "C" void kernel_launch(void* const* d_in, const int* in_sizes, int n_in,
                              void* d_out, int out_size, void* d_ws, size_t ws_size,
                              hipStream_t stream) {
    const float* depth   = (const float*)d_in[0];
    const float* density = (const float*)d_in[1];
    const float* feature = (const float*)d_in[2];
    float* out = (float*)d_out;

    dim3 grid(NBLOCKS);
    dim3 block(BLOCK);
    volrend_kernel<<<grid, block, 0, stream>>>(depth, density, feature, out);
}

// Round 4
// 194.456 us; speedup vs baseline: 1.1818x; 1.0008x over previous
//
#include <hip/hip_runtime.h>

#define N_RAYS 65536
#define N_PTS  128
#define FAR_DELTA 1e10f

#define BLOCK   256
#define NBLOCKS 1024                          // 4 blocks/CU, ALL resident (40 KB LDS each)
#define NWAVES  (NBLOCKS * (BLOCK / 64))      // 4096 waves
#define NPAIRS  (N_RAYS / 2)                  // 32768 ray-pairs
#define NP      (NPAIRS / NWAVES)             // 8 pairs per wave

// 2 rays per wave, staged via a double-buffered, wave-private global->LDS DMA
// pipeline. Per pair: 5 perfectly wave-contiguous 1-KB global_load_lds ops
// (depth 1, density 1, feature 3 -- the pair's 3072-B feature block is exactly
// 3 contiguous wave loads). DMA issue order is program order and the vmcnt
// literals are ours, so the compiler CANNOT sink the prefetch (round 3's
// failure: launch_bounds-capped VGPRs made the allocator delete the register
// pipeline). Issuing pair p+2 right after lgkmcnt(0) on pair p's LDS reads
// keeps 10 KB/wave in flight through every compute phase. No barriers, no
// cross-wave sharing, no mid-loop vmcnt(0).
__global__ __launch_bounds__(BLOCK) void volrend_kernel(
    const float* __restrict__ depth,
    const float* __restrict__ density,
    const float* __restrict__ feature,
    float* __restrict__ out)
{
    // [wave][buffer][slot*64] float4: 4 * 2 * 320 * 16 B = 40 KB
    __shared__ float4 sbuf[4][2][5 * 64];

    const int tid  = threadIdx.x;
    const int w    = tid >> 6;
    const int lane = tid & 63;
    const int sl   = lane & 31;               // lane within 32-lane ray segment
    const int g    = (int)blockIdx.x * (BLOCK / 64) + w;   // global wave id

#define GLD(gp_, lp_)                                                         \
    __builtin_amdgcn_global_load_lds(                                         \
        (const __attribute__((address_space(1))) void*)(gp_),                 \
        (__attribute__((address_space(3))) void*)(lp_), 16, 0, 0)

    // pair p_: depth/density blocks = 256 floats, feature block = 768 floats.
    // All 5 loads are wave-contiguous (lane's global addr = base + 16 B * lane;
    // LDS dest = wave-uniform slot base + lane*16, the linear-DMA layout).
#define ISSUE(p_, b_)                                                         \
    do {                                                                      \
        float4* wb_ = &sbuf[w][b_][0];                                        \
        GLD(depth   + (size_t)(p_) * 256 + 4 * lane, wb_);                    \
        GLD(density + (size_t)(p_) * 256 + 4 * lane, wb_ + 64);               \
        const float* fp_ = feature + (size_t)(p_) * 768 + 4 * lane;           \
        GLD(fp_,       wb_ + 128);                                            \
        GLD(fp_ + 256, wb_ + 192);                                            \
        GLD(fp_ + 512, wb_ + 256);                                            \
    } while (0)

    ISSUE(g, 0);
    ISSUE(NWAVES + g, 1);

#pragma unroll
    for (int p = 0; p < NP; ++p) {
        // vmcnt ledger (issue order: loads p,p+1 | per-step: +loads p+2, +store p):
        // p=0: [L0 L1]=10, drain L0 -> 5
        // p=1: [L1 L2 S0]=11, drain L1 -> 6
        // p in [2,NP-2]: [Lp S(p-2) L(p+1) S(p-1)]=12, drain Lp -> 7
        // p=NP-1: [S L(NP-1) S S]=8, drain L(NP-1) -> 2
        if      (p == 0)      asm volatile("s_waitcnt vmcnt(5)" ::: "memory");
        else if (p == 1)      asm volatile("s_waitcnt vmcnt(6)" ::: "memory");
        else if (p < NP - 1)  asm volatile("s_waitcnt vmcnt(7)" ::: "memory");
        else                  asm volatile("s_waitcnt vmcnt(2)" ::: "memory");

        const float4* wb = &sbuf[w][p & 1][0];
        float4 d   = wb[lane];            // lane's ray, samples 4sl..4sl+3
        float4 rho = wb[64 + lane];
        float4 f0  = wb[128 + 3 * lane];  // pair-block floats 12L..12L+11 ==
        float4 f1  = wb[129 + 3 * lane];  //   lane's ray row floats 12sl..12sl+11
        float4 f2  = wb[130 + 3 * lane];

        // buffer (p&1) is free for reuse once our ds_reads complete
        asm volatile("s_waitcnt lgkmcnt(0)" ::: "memory");
        if (p + 2 < NP) ISSUE((p + 2) * NWAVES + g, p & 1);

        // ---- taus + in-register local prefix (4 samples/lane) ----
        float nx = __shfl_down(d.x, 1);   // next lane's first depth
        float t0 = rho.x * (d.y - d.x);
        float t1 = rho.y * (d.z - d.y);
        float t2 = rho.z * (d.w - d.z);
        float t3 = rho.w * ((sl == 31) ? FAR_DELTA : (nx - d.w));
        float q1 = t0, q2 = q1 + t1, q3 = q2 + t2, tot = q3 + t3;

        // ---- 32-lane segmented exclusive scan (shift-then-inclusive; the
        //      sentinel tau of sl==31 never enters any exclusive sum) ----
        float e = __shfl_up(tot, 1);
        if (sl == 0) e = 0.0f;
        #pragma unroll
        for (int off = 1; off < 32; off <<= 1) {
            float u = __shfl_up(e, off);
            if (sl >= off) e += u;        // sl-guard masks cross-segment pulls
        }

        float T0 = __expf(-e);
        float T1 = __expf(-(e + q1));
        float T2 = __expf(-(e + q2));
        float T3 = __expf(-(e + q3));
        float T4 = __expf(-(e + tot));    // sl==31: exp(-1e10*rho) -> 0
        float w0 = T0 - T1, w1 = T1 - T2, w2 = T2 - T3, w3 = T3 - T4;

        float a3 = w0 * d.x  + w1 * d.y  + w2 * d.z  + w3 * d.w;
        float a0 = w0 * f0.x + w1 * f0.w + w2 * f1.z + w3 * f2.y;
        float a1 = w0 * f0.y + w1 * f1.x + w2 * f1.w + w3 * f2.z;
        float a2 = w0 * f0.z + w1 * f1.y + w2 * f2.x + w3 * f2.w;

        // ---- segmented reduction (xor butterfly stays inside 32 lanes) ----
        #pragma unroll
        for (int off = 16; off > 0; off >>= 1) {
            a0 += __shfl_xor(a0, off);
            a1 += __shfl_xor(a1, off);
            a2 += __shfl_xor(a2, off);
            a3 += __shfl_xor(a3, off);
        }
        if (sl == 0) {
            int ray = 2 * (p * NWAVES + g) + (lane >> 5);
            *(float4*)(out + (size_t)ray * 4) = make_float4(a0, a1, a2, a3);
        }
    }
#undef ISSUE
#undef GLD
}

extern "C" void kernel_launch(void* const* d_in, const int* in_sizes, int n_in,
                              void* d_out, int out_size, void* d_ws, size_t ws_size,
                              hipStream_t stream) {
    const float* depth   = (const float*)d_in[0];
    const float* density = (const float*)d_in[1];
    const float* feature = (const float*)d_in[2];
    float* out = (float*)d_out;

    dim3 grid(NBLOCKS);
    dim3 block(BLOCK);
    volrend_kernel<<<grid, block, 0, stream>>>(depth, density, feature, out);
}